// Round 1
// baseline (164.726 us; speedup 1.0000x reference)
//
#include <hip/hip_runtime.h>
#include <hip/hip_fp16.h>

// filtfilt for butter(4, 0.2) over rows of T=32768 fp32 samples.
// Key facts:
//  - reference's scale/unscale cancels exactly (everything is linear) -> skipped.
//  - filter poles |p|max ~= 0.796 -> warm-up of W samples kills IC error by 0.796^W.
//    WF=64 (4.5e-7), WB=48 (1.7e-5); threshold is 7e-2 absolute -> huge margin.
//  - forward intermediate kept per-thread in LDS as fp16 (err ~3e-3 abs, fine).

constexpr int kT     = 32768;
constexpr int kP     = 15;            // padlen = 3 * 5
constexpr int kText  = kT + 2 * kP;   // 32798
constexpr int kC     = 128;           // output samples per thread
constexpr int kWF    = 64;            // forward warm-up
constexpr int kWB    = 48;            // backward warm-up
constexpr int kNCh   = kT / kC;       // 256 chunks per row
constexpr int kStore = kC + kWB;      // 176 fwd samples kept
constexpr int kStride = kStore + 2;   // 178 halves: byte stride 356 -> bank (89*t + i/2)%32, 89%32=25 odd -> 2-way (free)
constexpr int kTPB   = 64;

#define B0 0.0048243445989025905f
#define B1 0.019297378395610362f
#define B2 0.028946067593415543f
#define B3 0.019297378395610362f
#define B4 0.0048243445989025905f
#define NA1 2.369513007182038f
#define NA2 (-2.3139884144002064f)
#define NA3 1.0546654058785661f
#define NA4 (-0.18737949236818502f)

// Direct-form II transposed step; z1 must read old z2, etc. (order matters).
#define STEP(xv) do { \
    y  = fmaf(B0, (xv), z1); \
    z1 = fmaf(NA1, y, fmaf(B1, (xv), z2)); \
    z2 = fmaf(NA2, y, fmaf(B2, (xv), z3)); \
    z3 = fmaf(NA3, y, fmaf(B3, (xv), z4)); \
    z4 = fmaf(NA4, y, B4 * (xv)); \
} while (0)

__global__ __launch_bounds__(kTPB, 2)
void filtfilt_kernel(const float* __restrict__ x, float* __restrict__ out) {
    __shared__ __half yfs[kTPB * kStride];   // 22784 B -> 7 blocks/CU
    const int tid   = blockIdx.x * kTPB + threadIdx.x;
    const int row   = tid >> 8;              // tid / kNCh
    const int chunk = tid & (kNCh - 1);
    const float* __restrict__ xr = x + (size_t)row * kT;
    float* __restrict__ outr     = out + (size_t)row * kT;
    __half* __restrict__ my      = yfs + threadIdx.x * kStride;

    const int s    = chunk * kC;                      // first output x-coord
    const int yb   = s + kP;                          // first stored ext-coord
    const int ye   = (yb + kStore < kText) ? (yb + kStore) : kText;
    const int L    = ye - yb;                         // 176 (last chunk: 143)
    const int nvec = (chunk == kNCh - 1) ? (kT - s) : L;  // in-bounds part of main loop

    float z1 = 0.f, z2 = 0.f, z3 = 0.f, z4 = 0.f, y;

    // ---------- forward pass ----------
    int idx = 0;
    {
        const float4* xp;
        int ng, gstore;
        if (chunk == 0) {
            // exact start: odd-extension region e in [0, 15), zero ICs
            #pragma unroll
            for (int e = 0; e < kP; ++e) {
                float xv = fmaf(2.f, xr[0], -xr[kP - e]);
                STEP(xv);
            }
            xp = (const float4*)xr; ng = nvec >> 2; gstore = 0;
        } else {
            // warm-up span [s-64, s) + main span, all interior, float4-aligned
            xp = (const float4*)(xr + s - kWF);
            ng = (kWF + nvec) >> 2; gstore = kWF >> 2;
        }
        float4 v = xp[0];
        for (int g = 0; g < ng; ++g) {
            int gn = (g + 1 < ng) ? (g + 1) : (ng - 1);
            float4 vn = xp[gn];                       // 1-ahead prefetch
            if (g >= gstore) {
                STEP(v.x); my[idx + 0] = __float2half(y);
                STEP(v.y); my[idx + 1] = __float2half(y);
                STEP(v.z); my[idx + 2] = __float2half(y);
                STEP(v.w); my[idx + 3] = __float2half(y);
                idx += 4;
            } else {
                STEP(v.x); STEP(v.y); STEP(v.z); STEP(v.w);
            }
            v = vn;
        }
        // right odd-extension tail (last chunk only)
        for (int i = nvec; i < L; ++i) {
            float xv = fmaf(2.f, xr[kT - 1], -xr[2 * kT - 2 - (s + i)]);
            STEP(xv);
            my[idx++] = __float2half(y);
        }
    }

    // ---------- backward pass ----------
    z1 = z2 = z3 = z4 = 0.f;
    // warm-up: ext coords (yb+L-1) down to (yb+kC); exact zero-IC at signal end for last chunk
    for (int i = L - 1; i >= kC; --i) {
        float v = __half2float(my[i]);
        STEP(v);
    }
    // main: 128 outputs, grouped float4 stores (descending)
    for (int gi = kC / 4 - 1; gi >= 0; --gi) {
        float4 o;
        float v;
        v = __half2float(my[gi * 4 + 3]); STEP(v); o.w = y;
        v = __half2float(my[gi * 4 + 2]); STEP(v); o.z = y;
        v = __half2float(my[gi * 4 + 1]); STEP(v); o.y = y;
        v = __half2float(my[gi * 4 + 0]); STEP(v); o.x = y;
        *(float4*)(outr + s + gi * 4) = o;
    }
}

extern "C" void kernel_launch(void* const* d_in, const int* in_sizes, int n_in,
                              void* d_out, int out_size, void* d_ws, size_t ws_size,
                              hipStream_t stream) {
    const float* x = (const float*)d_in[0];
    float* out     = (float*)d_out;
    const int rows = in_sizes[0] / kT;          // 512
    const int blocks = rows * kNCh / kTPB;      // 2048
    filtfilt_kernel<<<blocks, kTPB, 0, stream>>>(x, out);
}

// Round 2
// 138.734 us; speedup vs baseline: 1.1874x; 1.1874x over previous
//
#include <hip/hip_runtime.h>
#include <hip/hip_fp16.h>

// filtfilt for butter(4, 0.2) over rows of T=32768 fp32 samples.
//  - reference's scale/unscale cancels exactly (linear) -> skipped.
//  - poles |p|max ~= 0.796 -> warm-up W kills IC error by 0.796^W.
//    WF=64 (2e-6 abs), WB=28 (~8e-3 abs); threshold 7e-2 -> ok.
//  - forward intermediate per-thread in LDS as fp16 (~2e-3 abs).
//  - LDS = 20224 B/block -> exactly 8 blocks/CU -> full grid resident.
//  - fwd global loads: depth-8 float4 pipeline (hides ~600 cyc latency).

constexpr int kT      = 32768;
constexpr int kP      = 15;            // padlen = 3 * 5
constexpr int kText   = kT + 2 * kP;   // 32798
constexpr int kC      = 128;           // output samples per thread
constexpr int kWF     = 64;            // forward warm-up
constexpr int kWB     = 28;            // backward warm-up
constexpr int kNCh    = kT / kC;       // 256 chunks per row
constexpr int kStore  = kC + kWB;      // 156 fwd samples kept
constexpr int kStride = kStore + 2;    // 158 halves: byte stride 316 -> bank step 79 (odd) -> 2-way (free)
constexpr int kTPB    = 64;

#define B0 0.0048243445989025905f
#define B1 0.019297378395610362f
#define B2 0.028946067593415543f
#define B3 0.019297378395610362f
#define B4 0.0048243445989025905f
#define NA1 2.369513007182038f
#define NA2 (-2.3139884144002064f)
#define NA3 1.0546654058785661f
#define NA4 (-0.18737949236818502f)

// Direct-form II transposed step.
#define STEP(xv) do { \
    y  = fmaf(B0, (xv), z1); \
    z1 = fmaf(NA1, y, fmaf(B1, (xv), z2)); \
    z2 = fmaf(NA2, y, fmaf(B2, (xv), z3)); \
    z3 = fmaf(NA3, y, fmaf(B3, (xv), z4)); \
    z4 = fmaf(NA4, y, B4 * (xv)); \
} while (0)

__global__ __launch_bounds__(kTPB, 2)
void filtfilt_kernel(const float* __restrict__ x, float* __restrict__ out) {
    __shared__ __half yfs[kTPB * kStride];   // 20224 B -> 8 blocks/CU
    const int tid   = blockIdx.x * kTPB + threadIdx.x;
    const int row   = tid >> 8;              // tid / kNCh
    const int chunk = tid & (kNCh - 1);
    const float* __restrict__ xr = x + (size_t)row * kT;
    float* __restrict__ outr     = out + (size_t)row * kT;
    __half* __restrict__ my      = yfs + threadIdx.x * kStride;
    __half2* __restrict__ my2    = (__half2*)my;   // base byte 316*t, 4B-aligned

    const int s  = chunk * kC;                      // first output x-coord
    const int yb = s + kP;                          // first stored ext-coord
    const int ye = (yb + kStore < kText) ? (yb + kStore) : kText;
    const int L  = ye - yb;                         // 156 (last chunk: 143)
    const int nvec = (chunk == kNCh - 1) ? (kT - s) : L;

    float z1 = 0.f, z2 = 0.f, z3 = 0.f, z4 = 0.f, y;

    // ---------- forward pass ----------
    int idx = 0;
    {
        const float4* xp;
        int ng, gstore;
        if (chunk == 0) {
            // exact start: odd-extension region, zero ICs. Load x[0..15] vectorized.
            float xa[16];
            const float4* x4 = (const float4*)xr;
            *(float4*)&xa[0]  = x4[0];
            *(float4*)&xa[4]  = x4[1];
            *(float4*)&xa[8]  = x4[2];
            *(float4*)&xa[12] = x4[3];
            #pragma unroll
            for (int e = 0; e < kP; ++e) {
                float xv = fmaf(2.f, xa[0], -xa[kP - e]);
                STEP(xv);
            }
            xp = (const float4*)xr; ng = nvec >> 2; gstore = 0;       // ng=39
        } else {
            xp = (const float4*)(xr + s - kWF);
            ng = (kWF + nvec) >> 2; gstore = kWF >> 2;                // 55 (last: 48), 16
        }

        // depth-8 pipelined main loop (gstore is 0 or 16: uniform per 8-block)
        float4 buf[8];
        #pragma unroll
        for (int i = 0; i < 8; ++i) buf[i] = xp[i];
        const int ngm = ng & ~7;
        for (int g = 0; g < ngm; g += 8) {
            const bool st = (g >= gstore);
            #pragma unroll
            for (int u = 0; u < 8; ++u) {
                float4 v = buf[u];
                int pg = g + u + 8; pg = (pg < ng) ? pg : ng - 1;
                buf[u] = xp[pg];
                if (st) {
                    __half lo, hi;
                    STEP(v.x); lo = __float2half(y);
                    STEP(v.y); hi = __float2half(y);
                    my2[(idx >> 1) + 0] = __halves2half2(lo, hi);
                    STEP(v.z); lo = __float2half(y);
                    STEP(v.w); hi = __float2half(y);
                    my2[(idx >> 1) + 1] = __halves2half2(lo, hi);
                    idx += 4;
                } else {
                    STEP(v.x); STEP(v.y); STEP(v.z); STEP(v.w);
                }
            }
        }
        // remainder groups (always in store region: ngm >= gstore for all cases)
        #pragma unroll
        for (int u = 0; u < 8; ++u) {
            int g = ngm + u;
            if (g < ng) {
                float4 v = buf[u];
                __half lo, hi;
                STEP(v.x); lo = __float2half(y);
                STEP(v.y); hi = __float2half(y);
                my2[(idx >> 1) + 0] = __halves2half2(lo, hi);
                STEP(v.z); lo = __float2half(y);
                STEP(v.w); hi = __float2half(y);
                my2[(idx >> 1) + 1] = __halves2half2(lo, hi);
                idx += 4;
            }
        }
        // right odd-extension tail (last chunk only, 15 samples; x values are L1-hot)
        for (int i = nvec; i < L; ++i) {
            float xv = fmaf(2.f, xr[kT - 1], -xr[2 * kT - 2 - (s + i)]);
            STEP(xv);
            my[idx++] = __float2half(y);
        }
    }

    // ---------- backward pass ----------
    z1 = z2 = z3 = z4 = 0.f;
    if (L == kStore) {
        // vectorized warm-up: halves [128,156) = half2 idx 77..64, descending, zero ICs
        #pragma unroll
        for (int k = (kStore >> 1) - 1; k >= kC >> 1; --k) {
            float2 p = __half22float2(my2[k]);
            STEP(p.y); STEP(p.x);
        }
    } else {
        // last chunk: exact zero-IC warm-up over the 15 right-extension samples
        for (int i = L - 1; i >= kC; --i) {
            float v = __half2float(my[i]);
            STEP(v);
        }
    }
    // main: 16 blocks x 8 samples, with next-block LDS prefetch
    __half2 c0 = my2[60], c1 = my2[61], c2 = my2[62], c3 = my2[63];
    for (int b = 15; b >= 0; --b) {
        int nb = (b > 0) ? (b - 1) : 0;
        __half2 n0 = my2[4 * nb + 0], n1 = my2[4 * nb + 1],
                n2 = my2[4 * nb + 2], n3 = my2[4 * nb + 3];
        float4 o; float2 p;
        p = __half22float2(c3); STEP(p.y); o.w = y; STEP(p.x); o.z = y;
        p = __half22float2(c2); STEP(p.y); o.y = y; STEP(p.x); o.x = y;
        *(float4*)(outr + s + 8 * b + 4) = o;
        p = __half22float2(c1); STEP(p.y); o.w = y; STEP(p.x); o.z = y;
        p = __half22float2(c0); STEP(p.y); o.y = y; STEP(p.x); o.x = y;
        *(float4*)(outr + s + 8 * b) = o;
        c0 = n0; c1 = n1; c2 = n2; c3 = n3;
    }
}

extern "C" void kernel_launch(void* const* d_in, const int* in_sizes, int n_in,
                              void* d_out, int out_size, void* d_ws, size_t ws_size,
                              hipStream_t stream) {
    const float* x = (const float*)d_in[0];
    float* out     = (float*)d_out;
    const int rows = in_sizes[0] / kT;          // 512
    const int blocks = rows * kNCh / kTPB;      // 2048
    filtfilt_kernel<<<blocks, kTPB, 0, stream>>>(x, out);
}

// Round 3
// 131.762 us; speedup vs baseline: 1.2502x; 1.0529x over previous
//
#include <hip/hip_runtime.h>
#include <hip/hip_fp16.h>

// filtfilt butter(4,0.2), 512 rows x T=32768 fp32.
//  - scale/unscale is linear-homogeneous -> cancels exactly -> skipped.
//  - poles |p|max ~0.796: fwd warm-up 32 (7e-4), bwd warm-up 28 (~5e-3); thr 7e-2.
//  - per-thread chunk kC=64; forward intermediate held ENTIRELY IN REGISTERS
//    as fp16 (32 half2 archive + 14 half2 bwd-warm-up), all static indices.
//  - no LDS -> occupancy VGPR-limited: __launch_bounds__(64,4) caps VGPR<=128
//    -> 16 waves/CU, grid 4096 blocks = exactly 16 blocks/CU resident.

constexpr int kT   = 32768;
constexpr int kP   = 15;          // padlen
constexpr int kC   = 64;          // outputs per thread
constexpr int kWF  = 32;          // forward warm-up samples
constexpr int kNCh = kT / kC;     // 512 chunks/row
constexpr int kTPB = 64;

#define B0 0.0048243445989025905f
#define B1 0.019297378395610362f
#define B2 0.028946067593415543f
#define B3 0.019297378395610362f
#define B4 0.0048243445989025905f
#define NA1 2.369513007182038f
#define NA2 (-2.3139884144002064f)
#define NA3 1.0546654058785661f
#define NA4 (-0.18737949236818502f)

// Direct-form II transposed step.
#define STEP(xv) do { \
    y  = fmaf(B0, (xv), z1); \
    z1 = fmaf(NA1, y, fmaf(B1, (xv), z2)); \
    z2 = fmaf(NA2, y, fmaf(B2, (xv), z3)); \
    z3 = fmaf(NA3, y, fmaf(B3, (xv), z4)); \
    z4 = fmaf(NA4, y, B4 * (xv)); \
} while (0)

// two steps -> one packed half2 (static DST required)
#define PACK2(va, vb, DST) do { \
    STEP(va); __half _lo = __float2half(y); \
    STEP(vb); DST = __halves2half2(_lo, __float2half(y)); \
} while (0)

__global__ __launch_bounds__(kTPB, 4)
void filtfilt_kernel(const float* __restrict__ x, float* __restrict__ out) {
    const int tid   = blockIdx.x * kTPB + threadIdx.x;
    const int row   = tid >> 9;             // /kNCh
    const int chunk = tid & (kNCh - 1);
    const bool last = (chunk == kNCh - 1);
    const float* __restrict__ xr = x + (size_t)row * kT;
    float* __restrict__ outr     = out + (size_t)row * kT;
    const int s = chunk * kC;

    __half2 arc[kC / 2];   // stored fwd samples (ext coords [s+15, s+79))
    __half2 wu2[14];       // bwd warm-up samples (ext coords [s+79, s+107)); last: 15 tail

    float z1 = 0.f, z2 = 0.f, z3 = 0.f, z4 = 0.f, y;

    // ---------------- forward warm-up ----------------
    if (chunk == 0) {
        // exact: left odd-extension (ext 0..14), zero ICs
        float xa[16];
        const float4* x4 = (const float4*)xr;
        *(float4*)&xa[0] = x4[0]; *(float4*)&xa[4]  = x4[1];
        *(float4*)&xa[8] = x4[2]; *(float4*)&xa[12] = x4[3];
        #pragma unroll
        for (int e = 0; e < kP; ++e) {
            float xv = fmaf(2.f, xa[0], -xa[kP - e]);
            STEP(xv);
        }
    } else {
        // approx: 32 samples from x[s-32, s), zero ICs (error ~7e-4 by pole decay)
        const float4* wp = (const float4*)(xr + s - kWF);
        float4 w[8];
        #pragma unroll
        for (int i = 0; i < 8; ++i) w[i] = wp[i];
        #pragma unroll
        for (int i = 0; i < 8; ++i) {
            STEP(w[i].x); STEP(w[i].y); STEP(w[i].z); STEP(w[i].w);
        }
    }

    // ---------------- forward store: x[s, s+64) -> arc ----------------
    const float4* mp = (const float4*)(xr + s);
    float4 c0 = mp[0], c1 = mp[1], c2 = mp[2], c3 = mp[3];
    #pragma unroll
    for (int m = 0; m < 4; ++m) {
        float4 n0 = c0, n1 = c1, n2 = c2, n3 = c3;
        if (m < 3) {
            n0 = mp[4 * m + 4]; n1 = mp[4 * m + 5];
            n2 = mp[4 * m + 6]; n3 = mp[4 * m + 7];
        } else if (!last) {
            n0 = mp[16]; n1 = mp[17]; n2 = mp[18]; n3 = mp[19]; // wu groups
        }
        PACK2(c0.x, c0.y, arc[8 * m + 0]); PACK2(c0.z, c0.w, arc[8 * m + 1]);
        PACK2(c1.x, c1.y, arc[8 * m + 2]); PACK2(c1.z, c1.w, arc[8 * m + 3]);
        PACK2(c2.x, c2.y, arc[8 * m + 4]); PACK2(c2.z, c2.w, arc[8 * m + 5]);
        PACK2(c3.x, c3.y, arc[8 * m + 6]); PACK2(c3.z, c3.w, arc[8 * m + 7]);
        c0 = n0; c1 = n1; c2 = n2; c3 = n3;
    }

    // ---------------- forward continue: bwd warm-up samples ----------------
    if (!last) {
        // 28 samples x[s+64, s+92)  (c0..c3 already hold groups 16..19)
        float4 d0 = mp[20], d1 = mp[21], d2 = mp[22];
        PACK2(c0.x, c0.y, wu2[0]);  PACK2(c0.z, c0.w, wu2[1]);
        PACK2(c1.x, c1.y, wu2[2]);  PACK2(c1.z, c1.w, wu2[3]);
        PACK2(c2.x, c2.y, wu2[4]);  PACK2(c2.z, c2.w, wu2[5]);
        PACK2(c3.x, c3.y, wu2[6]);  PACK2(c3.z, c3.w, wu2[7]);
        PACK2(d0.x, d0.y, wu2[8]);  PACK2(d0.z, d0.w, wu2[9]);
        PACK2(d1.x, d1.y, wu2[10]); PACK2(d1.z, d1.w, wu2[11]);
        PACK2(d2.x, d2.y, wu2[12]); PACK2(d2.z, d2.w, wu2[13]);
    } else {
        // exact: 15 right-extension samples (ext kT+15 .. kT+29)
        float xa[16];
        const float4* e4 = (const float4*)(xr + kT - 16);
        *(float4*)&xa[0] = e4[0]; *(float4*)&xa[4]  = e4[1];
        *(float4*)&xa[8] = e4[2]; *(float4*)&xa[12] = e4[3];
        __half lo = __float2half(0.f);
        #pragma unroll
        for (int r = 0; r < 15; ++r) {
            float xv = fmaf(2.f, xa[15], -xa[14 - r]);  // 2x[T-1]-x[T-2-r]
            STEP(xv);
            if ((r & 1) == 0) lo = __float2half(y);
            else wu2[r >> 1] = __halves2half2(lo, __float2half(y));
        }
        wu2[7] = __halves2half2(lo, lo);  // r=14 pending in lo
    }

    // ---------------- backward warm-up (zero ICs; exact at signal end) ------
    z1 = z2 = z3 = z4 = 0.f;
    if (!last) {
        #pragma unroll
        for (int k = 13; k >= 0; --k) {
            float2 p = __half22float2(wu2[k]);
            STEP(p.y); STEP(p.x);
        }
    } else {
        { float2 p = __half22float2(wu2[7]); STEP(p.x); }  // sample j=14
        #pragma unroll
        for (int k = 6; k >= 0; --k) {
            float2 p = __half22float2(wu2[k]);
            STEP(p.y); STEP(p.x);
        }
    }

    // ---------------- backward main: 64 outputs, descending ----------------
    float4* op = (float4*)(outr + s);
    #pragma unroll
    for (int gi = 15; gi >= 0; --gi) {
        float2 pb = __half22float2(arc[2 * gi + 1]);
        float2 pa = __half22float2(arc[2 * gi]);
        float4 o;
        STEP(pb.y); o.w = y; STEP(pb.x); o.z = y;
        STEP(pa.y); o.y = y; STEP(pa.x); o.x = y;
        op[gi] = o;
    }
}

extern "C" void kernel_launch(void* const* d_in, const int* in_sizes, int n_in,
                              void* d_out, int out_size, void* d_ws, size_t ws_size,
                              hipStream_t stream) {
    const float* x = (const float*)d_in[0];
    float* out     = (float*)d_out;
    const int rows   = in_sizes[0] / kT;          // 512
    const int blocks = rows * kNCh / kTPB;        // 4096
    filtfilt_kernel<<<blocks, kTPB, 0, stream>>>(x, out);
}

// Round 5
// 131.096 us; speedup vs baseline: 1.2565x; 1.0051x over previous
//
#include <hip/hip_runtime.h>

// filtfilt butter(4,0.2), 512 rows x T=32768 fp32.
//  - reference's scale/unscale is linear-homogeneous -> cancels exactly -> skipped.
//  - poles |p|max ~0.796: fwd warm-up 32 (7e-4 abs), bwd warm-up 28 (~5e-3); thr 7e-2.
//  - per-thread chunk kC=64; forward intermediate held ENTIRELY IN REGISTERS as
//    packed fp16 pairs. CRITICAL: use native ext_vector_type(2) __fp16 (the
//    return type of __builtin_amdgcn_cvt_pkrtz), NOT __half2 (class type) —
//    __half2 arrays fail SROA and spill to scratch (R3: VGPR=56, WRITE_SIZE
//    140 MB = +70 MB scratch traffic).
//  - no LDS; __launch_bounds__(64,4) -> VGPR<=128 -> 16 waves/CU; grid 4096
//    blocks = exactly 16 blocks/CU, fully resident in one generation.

typedef __fp16 h2 __attribute__((ext_vector_type(2)));

constexpr int kT   = 32768;
constexpr int kP   = 15;          // padlen
constexpr int kC   = 64;          // outputs per thread
constexpr int kWF  = 32;          // forward warm-up samples
constexpr int kNCh = kT / kC;     // 512 chunks/row
constexpr int kTPB = 64;

#define B0 0.0048243445989025905f
#define B1 0.019297378395610362f
#define B2 0.028946067593415543f
#define B3 0.019297378395610362f
#define B4 0.0048243445989025905f
#define NA1 2.369513007182038f
#define NA2 (-2.3139884144002064f)
#define NA3 1.0546654058785661f
#define NA4 (-0.18737949236818502f)

// Direct-form II transposed step.
#define STEP(xv) do { \
    y  = fmaf(B0, (xv), z1); \
    z1 = fmaf(NA1, y, fmaf(B1, (xv), z2)); \
    z2 = fmaf(NA2, y, fmaf(B2, (xv), z3)); \
    z3 = fmaf(NA3, y, fmaf(B3, (xv), z4)); \
    z4 = fmaf(NA4, y, B4 * (xv)); \
} while (0)

// two steps -> one packed fp16 pair (v_cvt_pkrtz_f16_f32)
#define PACK2(va, vb, DST) do { \
    STEP(va); float _t = y; \
    STEP(vb); DST = __builtin_amdgcn_cvt_pkrtz(_t, y); \
} while (0)

__global__ __launch_bounds__(kTPB, 4)
void filtfilt_kernel(const float* __restrict__ x, float* __restrict__ out) {
    const int tid   = blockIdx.x * kTPB + threadIdx.x;
    const int row   = tid >> 9;             // /kNCh
    const int chunk = tid & (kNCh - 1);
    const bool last = (chunk == kNCh - 1);
    const float* __restrict__ xr = x + (size_t)row * kT;
    float* __restrict__ outr     = out + (size_t)row * kT;
    const int s = chunk * kC;

    h2 arc[kC / 2];   // stored fwd samples (ext coords [s+15, s+79))
    h2 wu[14];        // bwd warm-up samples; last chunk: 15 right-ext tail

    float z1 = 0.f, z2 = 0.f, z3 = 0.f, z4 = 0.f, y;

    // ---------------- forward warm-up ----------------
    if (chunk == 0) {
        // exact: left odd-extension (ext 0..14), zero ICs
        const float4* x4 = (const float4*)xr;
        float4 a0 = x4[0], a1 = x4[1], a2 = x4[2], a3 = x4[3];
        float xa[16] = {a0.x,a0.y,a0.z,a0.w, a1.x,a1.y,a1.z,a1.w,
                        a2.x,a2.y,a2.z,a2.w, a3.x,a3.y,a3.z,a3.w};
        #pragma unroll
        for (int e = 0; e < kP; ++e) {
            float xv = fmaf(2.f, xa[0], -xa[kP - e]);
            STEP(xv);
        }
    } else {
        // approx: 32 samples from x[s-32, s), zero ICs (pole decay ~7e-4)
        const float4* wp = (const float4*)(xr + s - kWF);
        float4 w[8];
        #pragma unroll
        for (int i = 0; i < 8; ++i) w[i] = wp[i];
        #pragma unroll
        for (int i = 0; i < 8; ++i) {
            STEP(w[i].x); STEP(w[i].y); STEP(w[i].z); STEP(w[i].w);
        }
    }

    // ---------------- forward store: x[s, s+64) -> arc ----------------
    const float4* mp = (const float4*)(xr + s);
    float4 c0 = mp[0], c1 = mp[1], c2 = mp[2], c3 = mp[3];
    #pragma unroll
    for (int m = 0; m < 4; ++m) {
        float4 n0 = c0, n1 = c1, n2 = c2, n3 = c3;
        if (m < 3) {
            n0 = mp[4 * m + 4]; n1 = mp[4 * m + 5];
            n2 = mp[4 * m + 6]; n3 = mp[4 * m + 7];
        } else if (!last) {
            n0 = mp[16]; n1 = mp[17]; n2 = mp[18]; n3 = mp[19]; // wu groups
        }
        PACK2(c0.x, c0.y, arc[8 * m + 0]); PACK2(c0.z, c0.w, arc[8 * m + 1]);
        PACK2(c1.x, c1.y, arc[8 * m + 2]); PACK2(c1.z, c1.w, arc[8 * m + 3]);
        PACK2(c2.x, c2.y, arc[8 * m + 4]); PACK2(c2.z, c2.w, arc[8 * m + 5]);
        PACK2(c3.x, c3.y, arc[8 * m + 6]); PACK2(c3.z, c3.w, arc[8 * m + 7]);
        c0 = n0; c1 = n1; c2 = n2; c3 = n3;
    }

    // ---------------- forward continue: bwd warm-up samples ----------------
    if (!last) {
        // 28 samples x[s+64, s+92)  (c0..c3 already hold groups 16..19)
        float4 d0 = mp[20], d1 = mp[21], d2 = mp[22];
        PACK2(c0.x, c0.y, wu[0]);  PACK2(c0.z, c0.w, wu[1]);
        PACK2(c1.x, c1.y, wu[2]);  PACK2(c1.z, c1.w, wu[3]);
        PACK2(c2.x, c2.y, wu[4]);  PACK2(c2.z, c2.w, wu[5]);
        PACK2(c3.x, c3.y, wu[6]);  PACK2(c3.z, c3.w, wu[7]);
        PACK2(d0.x, d0.y, wu[8]);  PACK2(d0.z, d0.w, wu[9]);
        PACK2(d1.x, d1.y, wu[10]); PACK2(d1.z, d1.w, wu[11]);
        PACK2(d2.x, d2.y, wu[12]); PACK2(d2.z, d2.w, wu[13]);
    } else {
        // exact: 15 right-odd-extension samples (2x[T-1]-x[T-2-r])
        const float4* e4 = (const float4*)(xr + kT - 16);
        float4 b0 = e4[0], b1 = e4[1], b2 = e4[2], b3 = e4[3];
        float xa[16] = {b0.x,b0.y,b0.z,b0.w, b1.x,b1.y,b1.z,b1.w,
                        b2.x,b2.y,b2.z,b2.w, b3.x,b3.y,b3.z,b3.w};
        float pend = 0.f;
        #pragma unroll
        for (int r = 0; r < 15; ++r) {
            float xv = fmaf(2.f, xa[15], -xa[14 - r]);
            STEP(xv);
            if ((r & 1) == 0) pend = y;
            else wu[r >> 1] = __builtin_amdgcn_cvt_pkrtz(pend, y);
        }
        wu[7] = __builtin_amdgcn_cvt_pkrtz(pend, pend);  // r=14 in .x
    }

    // ---------------- backward warm-up (zero ICs; exact at signal end) ------
    z1 = z2 = z3 = z4 = 0.f;
    if (!last) {
        #pragma unroll
        for (int k = 13; k >= 0; --k) {
            float a = (float)wu[k].y; STEP(a);
            float b = (float)wu[k].x; STEP(b);
        }
    } else {
        { float a = (float)wu[7].x; STEP(a); }   // tail sample r=14
        #pragma unroll
        for (int k = 6; k >= 0; --k) {
            float a = (float)wu[k].y; STEP(a);
            float b = (float)wu[k].x; STEP(b);
        }
    }

    // ---------------- backward main: 64 outputs, descending ----------------
    float4* op = (float4*)(outr + s);
    #pragma unroll
    for (int gi = 15; gi >= 0; --gi) {
        float4 o; float v;
        v = (float)arc[2 * gi + 1].y; STEP(v); o.w = y;
        v = (float)arc[2 * gi + 1].x; STEP(v); o.z = y;
        v = (float)arc[2 * gi + 0].y; STEP(v); o.y = y;
        v = (float)arc[2 * gi + 0].x; STEP(v); o.x = y;
        op[gi] = o;
    }
}

extern "C" void kernel_launch(void* const* d_in, const int* in_sizes, int n_in,
                              void* d_out, int out_size, void* d_ws, size_t ws_size,
                              hipStream_t stream) {
    const float* x = (const float*)d_in[0];
    float* out     = (float*)d_out;
    const int rows   = in_sizes[0] / kT;          // 512
    const int blocks = rows * kNCh / kTPB;        // 4096
    filtfilt_kernel<<<blocks, kTPB, 0, stream>>>(x, out);
}